// Round 6
// baseline (2681.488 us; speedup 1.0000x reference)
//
#include <hip/hip_runtime.h>
#include <stdint.h>

#define BB 4
#define NN 16384
#define NPOINT 1024
#define NSAMPLE 32
#define CC 64
#define RADIUS2 0.00999999977648258209228515625f
#define BIGF 1.0e10f

#define FT 1024  // fps threads per block (16 waves)
#define FK 16    // points per thread (FT*FK == NN)

typedef float f32x2 __attribute__((ext_vector_type(2)));

__device__ __forceinline__ f32x2 pk_add(f32x2 a, f32x2 b) {
    f32x2 d;
    asm("v_pk_add_f32 %0, %1, %2" : "=v"(d) : "v"(a), "v"(b));
    return d;
}
__device__ __forceinline__ f32x2 pk_mul(f32x2 a, f32x2 b) {
    f32x2 d;
    asm("v_pk_mul_f32 %0, %1, %2" : "=v"(d) : "v"(a), "v"(b));
    return d;
}

// ---------------- repack w1 (64x67) -> (64x68) padded, pad=0 ----------------
__global__ __launch_bounds__(256) void repack_w1(const float* __restrict__ w1,
                                                 float* __restrict__ w1p) {
    int t = threadIdx.x;
    for (int i = t; i < 64 * 68; i += 256) {
        int o = i / 68, c = i % 68;
        w1p[i] = (c < 67) ? w1[o * 67 + c] : 0.0f;
    }
}

// ---------------- stage: pack z coords contiguously into ws ----------------
__global__ __launch_bounds__(256) void fps_stage(const float* __restrict__ xyz,
                                                 float* __restrict__ zpack) {
    int g = blockIdx.x * 256 + threadIdx.x;  // 0..BB*NN-1
    int b = g / NN, p = g - b * NN;
    zpack[g] = xyz[(size_t)b * NN * 3 + 3 * p + 2];
}

// DPP-based argmax step (max value, min index on ties) — validated bit-exact.
template <int CTRL>
__device__ __forceinline__ void amax_step(float& v, int& i) {
    int nv = __builtin_amdgcn_update_dpp(__float_as_int(v), __float_as_int(v),
                                         CTRL, 0xf, 0xf, false);
    int ni = __builtin_amdgcn_update_dpp(i, i, CTRL, 0xf, 0xf, false);
    float fv = __int_as_float(nv);
    if (fv > v || (fv == v && ni < i)) { v = fv; i = ni; }
}
__device__ __forceinline__ void wave_amax(float& v, int& i) {
    amax_step<0x111>(v, i);  // row_shr:1
    amax_step<0x112>(v, i);  // row_shr:2
    amax_step<0x114>(v, i);  // row_shr:4
    amax_step<0x118>(v, i);  // row_shr:8
    amax_step<0x142>(v, i);  // row_bcast:15
    amax_step<0x143>(v, i);  // row_bcast:31  -> lane63 holds full wave result
}

// ---------------- FPS: one 1024-thread block per batch, coords in LDS -------
// R1-R5 lesson: the register allocator refuses to keep ~128 loaded coords
// live (spills to scratch -> 2.2us/iter of L2 re-streaming, VGPR_Count stuck
// at 48-84). So coords live in explicitly-managed LDS (x,y: 128KB dynamic)
// + a packed global z array (64KB/batch, L1/L2-resident). Only dd[] (computed
// state, 16 regs) relies on the RA -- that part always worked.
__global__ __launch_bounds__(FT)
void fps_kernel(const float* xyz, const float* zpack, float* new_xyz) {
    const int b = blockIdx.x;
    const int t = threadIdx.x;
    const int lane = t & 63;
    const int w = t >> 6;  // 0..15

    extern __shared__ float lds[];
    float2* xy = (float2*)lds;                  // [NN]  128 KB
    float2* slots = (float2*)(lds + 2 * NN);    // [2][16] parity reduce slots

    const float* xb = xyz + (size_t)b * NN * 3;
    const float* zp = zpack + (size_t)b * NN;

    // stage x,y into LDS (z comes pre-packed from fps_stage)
    for (int m = 0; m < 48; ++m) {
        int q = m * FT + t;            // flat float idx into xb, 0..3*NN-1
        float v = xb[q];
        int p = q / 3, c = q - 3 * p;
        if (c == 0) xy[p].x = v;
        else if (c == 1) xy[p].y = v;
    }
    __syncthreads();

    float dd[FK];
#pragma unroll
    for (int k = 0; k < FK; ++k) dd[k] = BIGF;

    // initial centroid = point 0
    float cx = xb[0], cy = xb[1], cz = xb[2];

    for (int i = 0; i < NPOINT; ++i) {
        // memory clobber: forbids hoisting the 16 LDS + 16 global coord loads
        // out of the i-loop (which would re-create the R1-R5 spill disaster)
        asm volatile("" ::: "memory");
        if (t == 0) {
            float* o = new_xyz + ((size_t)b * NPOINT + i) * 3;
            o[0] = cx; o[1] = cy; o[2] = cz;
        }
        f32x2 ncxy; ncxy.x = -cx; ncxy.y = -cy;
        float ncz = -cz;

        float bv = -1.0f;
        int bk = 0;
        // EXACT numpy semantics: sub = a+(-b) (exact), per-element RN mul,
        // sum order (dx^2+dy^2)+dz^2, min, strict > with ascending local k
        // -> first-occurrence argmax.
#pragma unroll
        for (int k = 0; k < FK; ++k) {
            int p = k * FT + t;
            float2 v2 = xy[p];               // ds_read_b64, stride-1
            float zv = zp[p];                // coalesced dword, L1/L2-hot
            f32x2 pxy; pxy.x = v2.x; pxy.y = v2.y;
            f32x2 dxy = pk_add(pxy, ncxy);
            f32x2 m2 = pk_mul(dxy, dxy);
            float dz = __fadd_rn(zv, ncz);
            float mz = __fmul_rn(dz, dz);
            float d = __fadd_rn(__fadd_rn(m2.x, m2.y), mz);
            float nd = fminf(dd[k], d);
            dd[k] = nd;
            bool c = nd > bv;
            bv = c ? nd : bv;
            bk = c ? k : bk;
        }
        int bi = bk * FT + t;  // global idx, monotone in k for fixed t

        wave_amax(bv, bi);
        if (lane == 63) slots[(i & 1) * 16 + w] = make_float2(bv, __int_as_float(bi));
        __syncthreads();

        // each lane reads one of the 16 wave slots (4-lane broadcast groups),
        // second wave reduce -> all lanes hold the global argmax
        float2 s = slots[(i & 1) * 16 + (lane & 15)];
        float v2 = s.x;
        int i2 = __float_as_int(s.y);
        wave_amax(v2, i2);
        int ixs = __builtin_amdgcn_readlane(i2, 63);  // uniform -> SGPR

        cx = xb[ixs * 3 + 0];
        cy = xb[ixs * 3 + 1];
        cz = xb[ixs * 3 + 2];
    }
}

// ---------------- ball query: one wave per centroid ----------------
__global__ __launch_bounds__(256) void ballquery_kernel(const float* __restrict__ xyz,
                                                        const float* __restrict__ new_xyz,
                                                        int* __restrict__ nidx) {
    const int t = threadIdx.x;
    const int lane = t & 63;
    const int w = t >> 6;
    const int cid = blockIdx.x * 4 + w;  // 0..4095
    const int b = cid >> 10;

    __shared__ int list[4][NSAMPLE];

    const float* xb = xyz + (size_t)b * NN * 3;
    const float* c = new_xyz + (size_t)cid * 3;
    float cx = c[0], cy = c[1], cz = c[2];

    int cnt = 0;
    for (int base = 0; base < NN && cnt < NSAMPLE; base += 64) {
        int j = base + lane;
        float dx = __fsub_rn(xb[j * 3 + 0], cx);
        float dy = __fsub_rn(xb[j * 3 + 1], cy);
        float dz = __fsub_rn(xb[j * 3 + 2], cz);
        float d2 = __fadd_rn(__fadd_rn(__fmul_rn(dx, dx), __fmul_rn(dy, dy)),
                             __fmul_rn(dz, dz));
        bool hit = d2 < RADIUS2;
        unsigned long long m = __ballot(hit);
        int pre = __popcll(m & ((1ull << lane) - 1ull));
        if (hit) {
            int pos = cnt + pre;
            if (pos < NSAMPLE) list[w][pos] = j;
        }
        cnt += __popcll(m);  // ballot result uniform -> cnt stays wave-uniform
    }
    __syncthreads();
    if (lane < NSAMPLE) {
        int first = list[w][0];  // >=1 hit always: centroid is a member point
        int v = (lane < cnt) ? list[w][lane] : first;
        nidx[(size_t)cid * NSAMPLE + lane] = v;
    }
}

// ---------------- grouped MLP + maxpool: one thread per (point,sample) ------
__global__ __launch_bounds__(256, 2) void mlp_kernel(
    const float* __restrict__ xyz, const float* __restrict__ features,
    const float* __restrict__ new_xyz, const int* __restrict__ nidx,
    const float* __restrict__ w1p, const float* __restrict__ b1,
    const float* __restrict__ w2, const float* __restrict__ b2,
    const float* __restrict__ w3, const float* __restrict__ b3,
    float* __restrict__ out) {
    const int gid = blockIdx.x * 256 + threadIdx.x;
    const int s = gid & 31;
    const int pg = gid >> 5;  // b*1024 + p
    const int b = pg >> 10;
    const int p = pg & 1023;

    const int idx = nidx[gid];
    const float* nc = new_xyz + (size_t)pg * 3;
    const float* pt = xyz + ((size_t)b * NN + idx) * 3;
    float gx = pt[0] - nc[0], gy = pt[1] - nc[1], gz = pt[2] - nc[2];

    float fin[64];
    const float4* fp = (const float4*)(features + ((size_t)b * NN + idx) * CC);
#pragma unroll
    for (int j = 0; j < 16; ++j) {
        float4 q = fp[j];
        fin[4 * j] = q.x; fin[4 * j + 1] = q.y;
        fin[4 * j + 2] = q.z; fin[4 * j + 3] = q.w;
    }

    float h1[64];
#pragma unroll
    for (int o = 0; o < 64; ++o) {
        const float4* wr = (const float4*)(w1p + o * 68);  // uniform -> s_load
        float acc = b1[o];
        float4 q0 = wr[0];
        acc = fmaf(q0.x, gx, acc);
        acc = fmaf(q0.y, gy, acc);
        acc = fmaf(q0.z, gz, acc);
        acc = fmaf(q0.w, fin[0], acc);
#pragma unroll
        for (int j = 1; j < 17; ++j) {
            float4 q = wr[j];
            int c0 = 4 * j - 3;
            acc = fmaf(q.x, fin[c0], acc);
            acc = fmaf(q.y, fin[c0 + 1], acc);
            acc = fmaf(q.z, fin[c0 + 2], acc);
            if (c0 + 3 < 64) acc = fmaf(q.w, fin[c0 + 3], acc);
        }
        h1[o] = fmaxf(acc, 0.0f);
    }

    float h2[64];
#pragma unroll
    for (int o = 0; o < 64; ++o) {
        const float4* wr = (const float4*)(w2 + o * 64);
        float acc = b2[o];
#pragma unroll
        for (int j = 0; j < 16; ++j) {
            float4 q = wr[j];
            acc = fmaf(q.x, h1[4 * j], acc);
            acc = fmaf(q.y, h1[4 * j + 1], acc);
            acc = fmaf(q.z, h1[4 * j + 2], acc);
            acc = fmaf(q.w, h1[4 * j + 3], acc);
        }
        h2[o] = fmaxf(acc, 0.0f);
    }

    float* ob = out + (size_t)b * 128 * NPOINT + p;
#pragma unroll
    for (int o = 0; o < 128; ++o) {
        const float4* wr = (const float4*)(w3 + o * 64);
        float acc = b3[o];
#pragma unroll
        for (int j = 0; j < 16; ++j) {
            float4 q = wr[j];
            acc = fmaf(q.x, h2[4 * j], acc);
            acc = fmaf(q.y, h2[4 * j + 1], acc);
            acc = fmaf(q.z, h2[4 * j + 2], acc);
            acc = fmaf(q.w, h2[4 * j + 3], acc);
        }
        float r = fmaxf(acc, 0.0f);
#pragma unroll
        for (int off = 1; off < 32; off <<= 1) {
            float orr = __shfl_xor(r, off);
            r = fmaxf(r, orr);
        }
        if (s == 0) ob[(size_t)o * NPOINT] = r;
    }
}

extern "C" void kernel_launch(void* const* d_in, const int* in_sizes, int n_in,
                              void* d_out, int out_size, void* d_ws, size_t ws_size,
                              hipStream_t stream) {
    const float* xyz = (const float*)d_in[0];
    const float* features = (const float*)d_in[1];
    const float* w1 = (const float*)d_in[2];
    const float* b1 = (const float*)d_in[3];
    const float* w2 = (const float*)d_in[4];
    const float* b2 = (const float*)d_in[5];
    const float* w3 = (const float*)d_in[6];
    const float* b3 = (const float*)d_in[7];

    float* out = (float*)d_out;
    float* new_xyz = out;                          // B*NPOINT*3
    float* new_feat = out + BB * NPOINT * 3;       // B*128*NPOINT

    char* ws = (char*)d_ws;
    int* nidx = (int*)ws;                                   // 512 KB
    float* w1p = (float*)(ws + (size_t)BB * NPOINT * NSAMPLE * 4);        // 17.4 KB
    float* zpack = (float*)(ws + (size_t)BB * NPOINT * NSAMPLE * 4 + 64 * 68 * 4);  // 256 KB

    // allow 128KB+ dynamic LDS for fps_kernel (host-side, graph-capture-safe)
    static const int lds_bytes = 2 * NN * (int)sizeof(float) + 2 * 16 * (int)sizeof(float2);
    hipFuncSetAttribute((const void*)fps_kernel,
                        hipFuncAttributeMaxDynamicSharedMemorySize, lds_bytes);

    hipLaunchKernelGGL(repack_w1, dim3(1), dim3(256), 0, stream, w1, w1p);
    hipLaunchKernelGGL(fps_stage, dim3(BB * NN / 256), dim3(256), 0, stream, xyz, zpack);
    hipLaunchKernelGGL(fps_kernel, dim3(BB), dim3(FT), lds_bytes, stream,
                       xyz, zpack, new_xyz);
    hipLaunchKernelGGL(ballquery_kernel, dim3(BB * NPOINT / 4), dim3(256), 0, stream,
                       xyz, new_xyz, nidx);
    hipLaunchKernelGGL(mlp_kernel, dim3(BB * NPOINT * NSAMPLE / 256), dim3(256), 0, stream,
                       xyz, features, new_xyz, nidx, w1p, b1, w2, b2, w3, b3, new_feat);
}